// Round 5
// baseline (42.166 us; speedup 1.0000x reference)
//
#include <hip/hip_runtime.h>

// Problem constants (match reference)
#define Bn 16
#define Kn 17
#define Hn 256
#define Wn 256
#define Mn 30
#define NFLAT (Kn * Hn * Wn)                   // 1,114,112 tags per image
#define TOTAL ((long long)Bn * Kn * Hn * Wn)   // 17,825,792 elements
#define NVEC  ((int)(TOTAL / 4))               // float4 count = 4,456,448 = 17 * 262144

#define HEAT_BLOCKS 1024                       // 4 blocks/CU exactly (256 CUs)
#define THREADS 256
#define ITERS 17                               // 1024*256*17 == NVEC exactly
#define TSTRIDE (HEAT_BLOCKS * THREADS)        // 262,144 threads
#define AE_BLOCKS Bn
#define NBLOCKS (HEAT_BLOCKS + AE_BLOCKS)

// ---------------------------------------------------------------------------
// Kernel 1: AE blocks [0,16) + heat MSE partial blocks [16, 16+1024)
// ---------------------------------------------------------------------------
__global__ __launch_bounds__(THREADS) void fused_kernel(
    const float4* __restrict__ pred,
    const float4* __restrict__ gt,
    const float4* __restrict__ mask,
    const float* __restrict__ tags,      // [B, NFLAT]
    const int* __restrict__ joints,      // [B, M, K, 2]
    float* __restrict__ partial,         // [HEAT_BLOCKS]
    float* __restrict__ push_arr,        // [Bn]
    float* __restrict__ pull_arr) {      // [Bn]
    __shared__ float smem[64];

    if (blockIdx.x >= AE_BLOCKS) {
        // ---------------- heatmap MSE partial (exact partition) -------------
        int hb = blockIdx.x - AE_BLOCKS;
        int t = hb * THREADS + threadIdx.x;
        const float4* P = pred + t;
        const float4* G = gt + t;
        const float4* M = mask + t;

        float acc0 = 0.f, acc1 = 0.f;
        // 1-deep software pipeline: next iteration's loads issue before
        // current iteration's compute consumes its values.
        float4 p = P[0], g = G[0], m = M[0];
#pragma unroll
        for (int it = 0; it < ITERS - 1; ++it) {
            int nx = (it + 1) * TSTRIDE;
            float4 pn = P[nx];
            float4 gn = G[nx];
            float4 mn = M[nx];
            float dx = p.x - g.x, dy = p.y - g.y, dz = p.z - g.z, dw = p.w - g.w;
            if (it & 1)
                acc1 += dx * dx * m.x + dy * dy * m.y + dz * dz * m.z + dw * dw * m.w;
            else
                acc0 += dx * dx * m.x + dy * dy * m.y + dz * dz * m.z + dw * dw * m.w;
            p = pn; g = gn; m = mn;
        }
        {
            float dx = p.x - g.x, dy = p.y - g.y, dz = p.z - g.z, dw = p.w - g.w;
            acc0 += dx * dx * m.x + dy * dy * m.y + dz * dz * m.z + dw * dw * m.w;
        }
        float a = acc0 + acc1;
        // intra-wave reduce (64 lanes)
        for (int off = 32; off > 0; off >>= 1) a += __shfl_down(a, off, 64);
        int wave = threadIdx.x >> 6;
        if ((threadIdx.x & 63) == 0) smem[wave] = a;
        __syncthreads();
        if (threadIdx.x == 0)
            partial[hb] = smem[0] + smem[1] + smem[2] + smem[3];
    } else {
        // ---------------- AE (push/pull) loss, one image per block ----------
        int b = blockIdx.x;
        int lane = threadIdx.x;  // only wave 0 (lanes 0..63) participates

        float mu = 0.f, pullpp = 0.f, validf = 0.f;
        if (lane < Mn) {
            const int* jb = joints + ((long long)(b * Mn + lane) * Kn) * 2;
            const float* tb = tags + (long long)b * NFLAT;
            float t[Kn], v[Kn];
            float cnt = 0.f, st = 0.f;
#pragma unroll
            for (int k = 0; k < Kn; k++) {
                int id = jb[2 * k];
                int vi = jb[2 * k + 1];
                float tv = tb[id];
                t[k] = tv;
                v[k] = (vi > 0) ? 1.f : 0.f;
                cnt += v[k];
                st += v[k] * tv;
            }
            float sc = fmaxf(cnt, 1.f);
            mu = st / sc;
            float pp = 0.f;
#pragma unroll
            for (int k = 0; k < Kn; k++) {
                float d = t[k] - mu;
                pp += v[k] * d * d;
            }
            pullpp = pp / sc;
            validf = (cnt > 0.f) ? 1.f : 0.f;
            smem[lane] = mu;          // mu in smem[0..29]
            smem[32 + lane] = validf; // valid in smem[32..61]
        }
        __syncthreads();

        if (lane < 64) {
            float nv = validf;
            float pv = (validf > 0.f) ? pullpp : 0.f;
            float sm = 0.f;
            if (lane < Mn && validf > 0.f) {
                for (int j = 0; j < Mn; j++) {
                    if (smem[32 + j] > 0.f) {
                        float d = mu - smem[j];
                        sm += expf(-(d * d));
                    }
                }
            }
            for (int off = 32; off > 0; off >>= 1) {
                nv += __shfl_down(nv, off, 64);
                pv += __shfl_down(pv, off, 64);
                sm += __shfl_down(sm, off, 64);
            }
            if (lane == 0) {
                float n = nv;
                float pull = pv / fmaxf(n, 1.f);
                float denom = fmaxf((n - 1.f) * n, 1.f);
                float push = (n >= 2.f) ? (sm - n) / denom * 0.5f : 0.f;
                push_arr[b] = push;
                pull_arr[b] = pull;
            }
        }
    }
}

// ---------------------------------------------------------------------------
// Kernel 2: finalize — reduce partials (double) + average push/pull
// ---------------------------------------------------------------------------
__global__ __launch_bounds__(256) void finalize_kernel(
    const float* __restrict__ partial,
    const float* __restrict__ push_arr,
    const float* __restrict__ pull_arr,
    float* __restrict__ out) {
    __shared__ double sd[256];
    double acc = 0.0;
    for (int i = threadIdx.x; i < HEAT_BLOCKS; i += 256) acc += (double)partial[i];
    sd[threadIdx.x] = acc;
    __syncthreads();
    for (int off = 128; off > 0; off >>= 1) {
        if (threadIdx.x < off) sd[threadIdx.x] += sd[threadIdx.x + off];
        __syncthreads();
    }
    if (threadIdx.x == 0) {
        double heat = sd[0] / (double)TOTAL;       // HEATMAPS_LOSS_FACTOR = 1.0
        float psum = 0.f, lsum = 0.f;
        for (int b = 0; b < Bn; b++) {
            psum += push_arr[b];
            lsum += pull_arr[b];
        }
        out[0] = (float)heat;
        out[1] = (psum / (float)Bn) * 0.001f;      // PUSH_LOSS_FACTOR
        out[2] = (lsum / (float)Bn) * 0.001f;      // PULL_LOSS_FACTOR
    }
}

// ---------------------------------------------------------------------------
extern "C" void kernel_launch(void* const* d_in, const int* in_sizes, int n_in,
                              void* d_out, int out_size, void* d_ws, size_t ws_size,
                              hipStream_t stream) {
    const float* heatmaps_pred = (const float*)d_in[0];
    const float* heatmaps      = (const float*)d_in[1];
    const float* masks         = (const float*)d_in[2];
    const float* tags_pred     = (const float*)d_in[3];
    const int*   joints        = (const int*)d_in[4];
    float* out = (float*)d_out;

    float* ws = (float*)d_ws;
    float* partial  = ws;                 // [HEAT_BLOCKS]
    float* push_arr = ws + HEAT_BLOCKS;   // [Bn]
    float* pull_arr = push_arr + Bn;      // [Bn]

    fused_kernel<<<NBLOCKS, THREADS, 0, stream>>>(
        (const float4*)heatmaps_pred, (const float4*)heatmaps,
        (const float4*)masks, tags_pred, joints, partial, push_arr, pull_arr);

    finalize_kernel<<<1, 256, 0, stream>>>(partial, push_arr, pull_arr, out);
}